// Round 2
// baseline (11959.839 us; speedup 1.0000x reference)
//
#include <hip/hip_runtime.h>

typedef unsigned int u32;
typedef float    f4  __attribute__((ext_vector_type(4)));
typedef _Float16 h2v __attribute__((ext_vector_type(2)));

#define B_ 32
#define T_ 2048
#define D_ 256
#define H_ 256
#define G_ 512  // 2H

// Precision note: the GRU recurrence has a mildly positive Lyapunov exponent
// (~5e-3/step): per-step injected error is amplified ~1e5x over T=2048. fp16
// anywhere in the loop (round-1: absmax 0.316) is fatal. Everything in the
// recurrent path is fp32: weights bit-exact fp32 in VGPRs, h fp32 in LDS,
// gx/cx fp32 in workspace. 768KB of fp32 recurrent weights exceed one CU's
// 512KB RF, so each batch element is split across a PAIR of workgroups
// (K-split 128+128) that exchange partial sums twice per step through
// agent-scope atomics.

__device__ __forceinline__ float fsigmoid(float x){
  return 1.f / (1.f + __expf(-x));
}
__device__ __forceinline__ float ftanh(float x){
  float a = fabsf(x);
  float e = __expf(2.f * a);
  float t = 1.f - 2.f / (e + 1.f);
  return copysignf(t, x);
}
__device__ __forceinline__ u32 pack2(float a, float b){
  h2v p = {(_Float16)a, (_Float16)b};
  return __builtin_bit_cast(u32, p);
}

// ---------------------------------------------------------------------------
// Phase 0: copy recurrent weights (fp32, bit-exact) into the per-thread
// register layout gru_pair consumes. Image j (=WG role) owns k in
// [128j, 128j+128). Thread t=(w*64+l), w<4, l<64:
//   reg r<256:  r=oi*32+kk -> Wg[256+128j+32w+kk][8l+oi]   (gate kernel, h-part)
//   reg r>=256: rc=r-256=oi*32+kk -> Wc[256+128j+32w+kk][4l+oi]
// Linear layout: wgp[j*98304 + r*256 + t]  (coalesced loads in gru_pair).
// ---------------------------------------------------------------------------
__global__ __launch_bounds__(256) void pack_w(
    const float* __restrict__ Wg, const float* __restrict__ Wc,
    float* __restrict__ wgp)
{
  int idx = blockIdx.x * 256 + threadIdx.x;          // [0, 196608)
  int j  = idx / 98304;
  int r2 = idx - j * 98304;
  int reg = r2 >> 8;
  int t   = r2 & 255;
  int w = t >> 6, l = t & 63;
  float v;
  if (reg < 256){
    int oi = reg >> 5, kk = reg & 31;
    v = Wg[(size_t)(256 + 128*j + 32*w + kk) * G_ + 8*l + oi];
  } else {
    int rc = reg - 256;
    int oi = rc >> 5, kk = rc & 31;
    v = Wc[(size_t)(256 + 128*j + 32*w + kk) * H_ + 4*l + oi];
  }
  wgp[idx] = v;
}

// ---------------------------------------------------------------------------
// Phase 1: Gx = X @ Wg[:256,:] + bg   [65536 x 512] fp32
//          Cx = X @ Wc[:256,:] + bc   [65536 x 256] fp32
// 64x64 fp32 LDS tile, 4x4 register tile per thread, N fused to 768.
// ---------------------------------------------------------------------------
__global__ __launch_bounds__(256) void input_proj(
    const float* __restrict__ X, const float* __restrict__ Wg, const float* __restrict__ bg,
    const float* __restrict__ Wc, const float* __restrict__ bc,
    float* __restrict__ gx, float* __restrict__ cx)
{
  __shared__ __align__(16) float At[16][64];   // [k][m]
  __shared__ __align__(16) float Bt[16][64];   // [k][n]
  const int t  = threadIdx.x;
  const int m0 = blockIdx.x*64, n0 = blockIdx.y*64;
  const int tm = (t & 15)*4, tn = (t >> 4)*4;
  const int lm = t >> 2,  lk = (t & 3)*4;
  const int bk = t >> 4,  bn = (t & 15)*4;
  const float* bsrc; int bld;
  if (n0 < G_) { bsrc = Wg + n0; bld = G_; } else { bsrc = Wc + (n0 - G_); bld = H_; }
  float acc[4][4] = {};
  for (int kc = 0; kc < D_; kc += 16){
    __syncthreads();
    f4 a4 = *(const f4*)&X[(size_t)(m0+lm)*D_ + kc + lk];
    f4 b4 = *(const f4*)&bsrc[(size_t)(kc+bk)*bld + bn];
    At[lk+0][lm] = a4.x; At[lk+1][lm] = a4.y; At[lk+2][lm] = a4.z; At[lk+3][lm] = a4.w;
    *(f4*)&Bt[bk][bn] = b4;
    __syncthreads();
#pragma unroll
    for (int k = 0; k < 16; ++k){
      f4 av = *(const f4*)&At[k][tm];
      f4 bv = *(const f4*)&Bt[k][tn];
#pragma unroll
      for (int i = 0; i < 4; ++i){
        acc[i][0] = fmaf(av[i], bv[0], acc[i][0]);
        acc[i][1] = fmaf(av[i], bv[1], acc[i][1]);
        acc[i][2] = fmaf(av[i], bv[2], acc[i][2]);
        acc[i][3] = fmaf(av[i], bv[3], acc[i][3]);
      }
    }
  }
  if (n0 < G_){
    f4 bb = { bg[n0+tn], bg[n0+tn+1], bg[n0+tn+2], bg[n0+tn+3] };
#pragma unroll
    for (int i = 0; i < 4; ++i){
      f4 v = { acc[i][0]+bb.x, acc[i][1]+bb.y, acc[i][2]+bb.z, acc[i][3]+bb.w };
      *(f4*)&gx[(size_t)(m0+tm+i)*G_ + n0 + tn] = v;
    }
  } else {
    int nn = n0 - G_;
    f4 bb = { bc[nn+tn], bc[nn+tn+1], bc[nn+tn+2], bc[nn+tn+3] };
#pragma unroll
    for (int i = 0; i < 4; ++i){
      f4 v = { acc[i][0]+bb.x, acc[i][1]+bb.y, acc[i][2]+bb.z, acc[i][3]+bb.w };
      *(f4*)&cx[(size_t)(m0+tm+i)*H_ + nn + tn] = v;
    }
  }
}

// ---------------------------------------------------------------------------
// Phase 2: sequential GRU, fp32-exact. Pair of WGs per batch element:
// blockIdx = j*32 + b (pair (b, b+32): same-XCD heuristic). WG j owns
// k in [128j, 128j+128) of both recurrent GEMVs; per-step partial sums are
// exchanged via agent-scope release/acquire flags (one fresh flag word per
// step -> 0xAA workspace poison can never false-trigger the equality check).
// The pair is mutually dependent each step => self-lockstepping, no overrun.
// ---------------------------------------------------------------------------
__global__ __launch_bounds__(256, 1) void gru_pair(
    const float* __restrict__ gx,      // [B][T][512] fp32, bias baked
    const float* __restrict__ cx,      // [B][T][256] fp32, bias baked
    const float* __restrict__ wgp,     // packed fp32 recurrent weights
    float* __restrict__ pay1, float* __restrict__ pay2,
    u32* __restrict__ flags,
    unsigned short* __restrict__ hseq) // [B][T][256] fp16 (output path only)
{
  __shared__ __align__(16) float part1[4][512];
  __shared__ __align__(16) float part2[4][256];
  __shared__ __align__(16) float h32[256];    // fp32 master h (replicated in both WGs)
  __shared__ __align__(16) float rh32[256];   // r .* h
  __shared__ __align__(16) float ug[256];     // update gate u

  const int tid = threadIdx.x;
  const int w = tid >> 6, l = tid & 63;
  const int b = blockIdx.x & 31;
  const int j = blockIdx.x >> 5;
  const int K0 = 128 * j;

  // -- load this WG's weight image into VGPRs (384 regs/thread, ~460 total,
  //    fits at 1 wave/SIMD with __launch_bounds__(256,1)) --
  const float* wbase = wgp + (size_t)j * 98304;
  float wg[256];
#pragma unroll
  for (int r = 0; r < 256; ++r) wg[r] = wbase[(size_t)r*256 + tid];
  float wc[128];
#pragma unroll
  for (int r = 0; r < 128; ++r) wc[r] = wbase[(size_t)(256+r)*256 + tid];

  h32[tid] = 0.f;
  __syncthreads();

  const float* gxb = gx + (size_t)b * T_ * G_;
  const float* cxb = cx + (size_t)b * T_ * H_;
  unsigned short* hb = hseq + (size_t)b * T_ * H_;

  float* p1own = pay1 + (size_t)(b*2 + j)     * 2 * 512;
  float* p1oth = pay1 + (size_t)(b*2 + (1-j)) * 2 * 512;
  float* p2own = pay2 + (size_t)(b*2 + j)     * 2 * 256;
  float* p2oth = pay2 + (size_t)(b*2 + (1-j)) * 2 * 256;
  u32* f1own = flags + ((size_t)((b*2 + j)*2 + 0) << 11);
  u32* f2own = flags + ((size_t)((b*2 + j)*2 + 1) << 11);
  u32* f1oth = flags + ((size_t)((b*2 + (1-j))*2 + 0) << 11);
  u32* f2oth = flags + ((size_t)((b*2 + (1-j))*2 + 1) << 11);

  for (int t = 0; t < T_; ++t){
    const int par = t & 1;
    // prefetch this step's gx/cx early (consumed after the first handshake)
    f4 g4 = {0.f,0.f,0.f,0.f}, c4 = {0.f,0.f,0.f,0.f};
    if (tid < 128) g4 = *(const f4*)(gxb + (size_t)t*G_ + 4*tid);
    if (tid < 64)  c4 = *(const f4*)(cxb + (size_t)t*H_ + 4*tid);

    // ---- GEMV1 partial over own k-range: pre_ru[o] += sum_k h[k]*Wgh[k][o] ----
    float hh[32];
#pragma unroll
    for (int i = 0; i < 32; i += 4) *(f4*)&hh[i] = *(const f4*)&h32[K0 + 32*w + i];
    float acc[8];
#pragma unroll
    for (int oi = 0; oi < 8; ++oi){
      float a = 0.f;
#pragma unroll
      for (int kk = 0; kk < 32; ++kk) a = fmaf(wg[oi*32 + kk], hh[kk], a);
      acc[oi] = a;
    }
    { f4 v0 = {acc[0],acc[1],acc[2],acc[3]};
      f4 v1 = {acc[4],acc[5],acc[6],acc[7]};
      *(f4*)&part1[w][8*l]     = v0;
      *(f4*)&part1[w][8*l + 4] = v1; }
    __syncthreads();                                   // (A)

    f4 own1 = {0.f,0.f,0.f,0.f};
    if (tid < 128){
      own1 = *(const f4*)&part1[0][4*tid];
#pragma unroll
      for (int ww = 1; ww < 4; ++ww) own1 += *(const f4*)&part1[ww][4*tid];
      *(f4*)(p1own + par*512 + 4*tid) = own1;
    }
    __syncthreads();  // (B) waitcnt vmcnt(0)+barrier: all payload stores done
    if (tid == 0){
      __hip_atomic_store(f1own + t, (u32)(t+1), __ATOMIC_RELEASE, __HIP_MEMORY_SCOPE_AGENT);
      while (__hip_atomic_load(f1oth + t, __ATOMIC_ACQUIRE, __HIP_MEMORY_SCOPE_AGENT) != (u32)(t+1))
        __builtin_amdgcn_s_sleep(1);
    }
    __syncthreads();                                   // (C)

    // ---- gates: r (own rh for all 256, redundant) and u ----
    if (tid < 128){
      f4 oth1 = *(const f4*)(p1oth + par*512 + 4*tid);
      f4 pre = g4 + own1 + oth1;
      if (tid < 64){
        f4 r;
        r.x = fsigmoid(pre.x); r.y = fsigmoid(pre.y);
        r.z = fsigmoid(pre.z); r.w = fsigmoid(pre.w);
        f4 hv = *(const f4*)&h32[4*tid];
        *(f4*)&rh32[4*tid] = r * hv;
      } else {
        f4 uv;
        uv.x = fsigmoid(pre.x); uv.y = fsigmoid(pre.y);
        uv.z = fsigmoid(pre.z); uv.w = fsigmoid(pre.w);
        *(f4*)&ug[4*tid - 256] = uv;
      }
    }
    __syncthreads();                                   // (D)

    // ---- GEMV2 partial over own k-range: pre_c[o] += sum_k rh[k]*Wch[k][o] ----
    float rr[32];
#pragma unroll
    for (int i = 0; i < 32; i += 4) *(f4*)&rr[i] = *(const f4*)&rh32[K0 + 32*w + i];
    float ac2[4];
#pragma unroll
    for (int oi = 0; oi < 4; ++oi){
      float a = 0.f;
#pragma unroll
      for (int kk = 0; kk < 32; ++kk) a = fmaf(wc[oi*32 + kk], rr[kk], a);
      ac2[oi] = a;
    }
    { f4 v = {ac2[0],ac2[1],ac2[2],ac2[3]};
      *(f4*)&part2[w][4*l] = v; }
    __syncthreads();                                   // (E)

    f4 own2 = {0.f,0.f,0.f,0.f};
    if (tid < 64){
      own2 = *(const f4*)&part2[0][4*tid];
#pragma unroll
      for (int ww = 1; ww < 4; ++ww) own2 += *(const f4*)&part2[ww][4*tid];
      *(f4*)(p2own + par*256 + 4*tid) = own2;
    }
    __syncthreads();                                   // (F)
    if (tid == 0){
      __hip_atomic_store(f2own + t, (u32)(t+1), __ATOMIC_RELEASE, __HIP_MEMORY_SCOPE_AGENT);
      while (__hip_atomic_load(f2oth + t, __ATOMIC_ACQUIRE, __HIP_MEMORY_SCOPE_AGENT) != (u32)(t+1))
        __builtin_amdgcn_s_sleep(1);
    }
    __syncthreads();                                   // (G)

    // ---- candidate, h update (redundant full h in both WGs) ----
    if (tid < 64){
      f4 oth2 = *(const f4*)(p2oth + par*256 + 4*tid);
      f4 pre2 = c4 + own2 + oth2;
      f4 cv;
      cv.x = ftanh(pre2.x); cv.y = ftanh(pre2.y);
      cv.z = ftanh(pre2.z); cv.w = ftanh(pre2.w);
      f4 uv = *(const f4*)&ug[4*tid];
      f4 hv = *(const f4*)&h32[4*tid];
      f4 one = {1.f,1.f,1.f,1.f};
      f4 hn = uv*hv + (one - uv)*cv;
      *(f4*)&h32[4*tid] = hn;
      if (j == 0){
        uint2 pk;
        pk.x = pack2(hn.x, hn.y);
        pk.y = pack2(hn.z, hn.w);
        *(uint2*)(hb + (size_t)t*H_ + 4*tid) = pk;
      }
    }
    __syncthreads();                                   // (H)
  }
}

// ---------------------------------------------------------------------------
// Phase 3: out = sigmoid(Hseq @ Wp + bp); fp16 A (output path only -> error
// ~6e-5, no feedback), fp32 B/out. 64x64 tiles.
// ---------------------------------------------------------------------------
__global__ __launch_bounds__(256) void out_proj(
    const unsigned short* __restrict__ hs, const float* __restrict__ Wp,
    const float* __restrict__ bp, float* __restrict__ out)
{
  __shared__ __align__(16) float At[16][64];
  __shared__ __align__(16) float Bt[16][64];
  const int t  = threadIdx.x;
  const int m0 = blockIdx.x*64, n0 = blockIdx.y*64;
  const int tm = (t & 15)*4, tn = (t >> 4)*4;
  const int lm = t >> 2,  lk = (t & 3)*4;
  const int bk = t >> 4,  bn = (t & 15)*4;
  float acc[4][4] = {};
  for (int kc = 0; kc < H_; kc += 16){
    __syncthreads();
    uint2 a2 = *(const uint2*)(hs + (size_t)(m0+lm)*H_ + kc + lk);
    f4  b4 = *(const f4*)&Wp[(size_t)(kc+bk)*256 + n0 + bn];
    h2v a0 = __builtin_bit_cast(h2v, a2.x), a1 = __builtin_bit_cast(h2v, a2.y);
    At[lk+0][lm] = (float)a0.x; At[lk+1][lm] = (float)a0.y;
    At[lk+2][lm] = (float)a1.x; At[lk+3][lm] = (float)a1.y;
    *(f4*)&Bt[bk][bn] = b4;
    __syncthreads();
#pragma unroll
    for (int k = 0; k < 16; ++k){
      f4 av = *(const f4*)&At[k][tm];
      f4 bv = *(const f4*)&Bt[k][tn];
#pragma unroll
      for (int i = 0; i < 4; ++i){
        acc[i][0] = fmaf(av[i], bv[0], acc[i][0]);
        acc[i][1] = fmaf(av[i], bv[1], acc[i][1]);
        acc[i][2] = fmaf(av[i], bv[2], acc[i][2]);
        acc[i][3] = fmaf(av[i], bv[3], acc[i][3]);
      }
    }
  }
  float b0=bp[n0+tn], b1=bp[n0+tn+1], b2=bp[n0+tn+2], b3=bp[n0+tn+3];
#pragma unroll
  for (int i = 0; i < 4; ++i){
    f4 r;
    r.x = fsigmoid(acc[i][0]+b0); r.y = fsigmoid(acc[i][1]+b1);
    r.z = fsigmoid(acc[i][2]+b2); r.w = fsigmoid(acc[i][3]+b3);
    *(f4*)&out[(size_t)(m0+tm+i)*256 + n0 + tn] = r;
  }
}

// ---------------------------------------------------------------------------
extern "C" void kernel_launch(void* const* d_in, const int* in_sizes, int n_in,
                              void* d_out, int out_size, void* d_ws, size_t ws_size,
                              hipStream_t stream)
{
  const float* x  = (const float*)d_in[0];
  const float* Wg = (const float*)d_in[1];
  const float* bg = (const float*)d_in[2];
  const float* Wc = (const float*)d_in[3];
  const float* bc = (const float*)d_in[4];
  const float* Wp = (const float*)d_in[5];
  const float* bp = (const float*)d_in[6];
  float* out = (float*)d_out;

  char* ws = (char*)d_ws;
  // layout (bytes):
  //   Gx    @ 0         : 32*2048*512*4 = 134217728
  //   Cx    @ 134217728 : 32*2048*256*4 =  67108864
  //   Hs    @ 201326592 : 32*2048*256*2 =  33554432  (fp16)
  //   wgp   @ 234881024 : 196608*4      =    786432
  //   pay1  @ 235667456 : 64*2*512*4    =    262144
  //   pay2  @ 235929600 : 64*2*256*4    =    131072
  //   flags @ 236060672 : 64*2*2048*4   =   1048576
  float* Gx = (float*)(ws);
  float* Cx = (float*)(ws + (size_t)134217728);
  unsigned short* Hs = (unsigned short*)(ws + (size_t)201326592);
  float* wgp = (float*)(ws + (size_t)234881024);
  float* pay1 = (float*)(ws + (size_t)235667456);
  float* pay2 = (float*)(ws + (size_t)235929600);
  u32* flags = (u32*)(ws + (size_t)236060672);

  pack_w<<<768, 256, 0, stream>>>(Wg, Wc, wgp);
  input_proj<<<dim3(1024, 12), 256, 0, stream>>>(x, Wg, bg, Wc, bc, Gx, Cx);
  gru_pair<<<64, 256, 0, stream>>>(Gx, Cx, wgp, pay1, pay2, flags, Hs);
  out_proj<<<dim3(1024, 4), 256, 0, stream>>>(Hs, Wp, bp, out);
}

// Round 3
// 11563.564 us; speedup vs baseline: 1.0343x; 1.0343x over previous
//
#include <hip/hip_runtime.h>

typedef unsigned int u32;
typedef float    f4  __attribute__((ext_vector_type(4)));
typedef _Float16 h2v __attribute__((ext_vector_type(2)));

#define B_ 32
#define T_ 2048
#define D_ 256
#define H_ 256
#define G_ 512  // 2H

// Precision: GRU recurrence amplifies per-step error ~6e4x over T=2048
// (round-1 fp16 loop: absmax 0.316; round-2 fp32 loop: 0.0039). Everything
// in the recurrent path stays fp32.
// Capacity: 768KB fp32 recurrent weights > one CU's 512KB RF -> pair of WGs
// per batch element (K-split 128+128), agent-scope flag handshakes.
// Round-2 lesson: a wave addresses at most 256 arch VGPRs; 384 floats/thread
// spilled (VGPR_Count=224, 13.8k cy/step, VALUBusy 3.4%). Now 512 thr/WG,
// 192 weight floats/thread, ~240 live regs -> true VGPR residency.

__device__ __forceinline__ float fsigmoid(float x){
  return 1.f / (1.f + __expf(-x));
}
__device__ __forceinline__ float ftanh(float x){
  float a = fabsf(x);
  float e = __expf(2.f * a);
  float t = 1.f - 2.f / (e + 1.f);
  return copysignf(t, x);
}
__device__ __forceinline__ u32 pack2(float a, float b){
  h2v p = {(_Float16)a, (_Float16)b};
  return __builtin_bit_cast(u32, p);
}

// ---------------------------------------------------------------------------
// Phase 0: pack recurrent weights (fp32 bit-exact) into gru_pair's register
// layout. WG image j owns k in [128j, 128j+128). Thread t in [0,512):
// wave w=t>>6, a=w&3 (k-slice of 32), bgrp=w>>2 (out-half), lane l=t&63.
//   r in [0,128):  oi=r>>5, c=(r>>4)&1, kk=r&15
//                  -> Wg[256+128j+32a+16c+kk][256*bgrp + 64*oi + l]
//   r in [128,192): rc=r-128: oi2=rc>>5, c=(rc>>4)&1, kk=rc&15
//                  -> Wc[256+128j+32a+16c+kk][128*bgrp + 64*oi2 + l]
// Linear: wgp[j*98304 + r*512 + t]  (coalesced in gru_pair's preamble).
// ---------------------------------------------------------------------------
__global__ __launch_bounds__(256) void pack_w(
    const float* __restrict__ Wg, const float* __restrict__ Wc,
    float* __restrict__ wgp)
{
  int idx = blockIdx.x * 256 + threadIdx.x;          // [0, 196608)
  int j  = idx / 98304;
  int r2 = idx - j * 98304;
  int r = r2 >> 9;
  int t = r2 & 511;
  int w = t >> 6, l = t & 63;
  int a = w & 3, bgrp = w >> 2;
  float v;
  if (r < 128){
    int oi = r >> 5, c = (r >> 4) & 1, kk = r & 15;
    v = Wg[(size_t)(256 + 128*j + 32*a + 16*c + kk) * G_ + 256*bgrp + 64*oi + l];
  } else {
    int rc = r - 128;
    int oi2 = rc >> 5, c = (rc >> 4) & 1, kk = rc & 15;
    v = Wc[(size_t)(256 + 128*j + 32*a + 16*c + kk) * H_ + 128*bgrp + 64*oi2 + l];
  }
  wgp[idx] = v;
}

// ---------------------------------------------------------------------------
// Phase 1: Gx = X @ Wg[:256,:] + bg   [65536 x 512] fp32
//          Cx = X @ Wc[:256,:] + bc   [65536 x 256] fp32
// ---------------------------------------------------------------------------
__global__ __launch_bounds__(256) void input_proj(
    const float* __restrict__ X, const float* __restrict__ Wg, const float* __restrict__ bg,
    const float* __restrict__ Wc, const float* __restrict__ bc,
    float* __restrict__ gx, float* __restrict__ cx)
{
  __shared__ __align__(16) float At[16][64];   // [k][m]
  __shared__ __align__(16) float Bt[16][64];   // [k][n]
  const int t  = threadIdx.x;
  const int m0 = blockIdx.x*64, n0 = blockIdx.y*64;
  const int tm = (t & 15)*4, tn = (t >> 4)*4;
  const int lm = t >> 2,  lk = (t & 3)*4;
  const int bk = t >> 4,  bn = (t & 15)*4;
  const float* bsrc; int bld;
  if (n0 < G_) { bsrc = Wg + n0; bld = G_; } else { bsrc = Wc + (n0 - G_); bld = H_; }
  float acc[4][4] = {};
  for (int kc = 0; kc < D_; kc += 16){
    __syncthreads();
    f4 a4 = *(const f4*)&X[(size_t)(m0+lm)*D_ + kc + lk];
    f4 b4 = *(const f4*)&bsrc[(size_t)(kc+bk)*bld + bn];
    At[lk+0][lm] = a4.x; At[lk+1][lm] = a4.y; At[lk+2][lm] = a4.z; At[lk+3][lm] = a4.w;
    *(f4*)&Bt[bk][bn] = b4;
    __syncthreads();
#pragma unroll
    for (int k = 0; k < 16; ++k){
      f4 av = *(const f4*)&At[k][tm];
      f4 bv = *(const f4*)&Bt[k][tn];
#pragma unroll
      for (int i = 0; i < 4; ++i){
        acc[i][0] = fmaf(av[i], bv[0], acc[i][0]);
        acc[i][1] = fmaf(av[i], bv[1], acc[i][1]);
        acc[i][2] = fmaf(av[i], bv[2], acc[i][2]);
        acc[i][3] = fmaf(av[i], bv[3], acc[i][3]);
      }
    }
  }
  if (n0 < G_){
    f4 bb = { bg[n0+tn], bg[n0+tn+1], bg[n0+tn+2], bg[n0+tn+3] };
#pragma unroll
    for (int i = 0; i < 4; ++i){
      f4 v = { acc[i][0]+bb.x, acc[i][1]+bb.y, acc[i][2]+bb.z, acc[i][3]+bb.w };
      *(f4*)&gx[(size_t)(m0+tm+i)*G_ + n0 + tn] = v;
    }
  } else {
    int nn = n0 - G_;
    f4 bb = { bc[nn+tn], bc[nn+tn+1], bc[nn+tn+2], bc[nn+tn+3] };
#pragma unroll
    for (int i = 0; i < 4; ++i){
      f4 v = { acc[i][0]+bb.x, acc[i][1]+bb.y, acc[i][2]+bb.z, acc[i][3]+bb.w };
      *(f4*)&cx[(size_t)(m0+tm+i)*H_ + nn + tn] = v;
    }
  }
}

// ---------------------------------------------------------------------------
// Phase 2: sequential GRU, fp32-exact, 512 threads/WG, pair of WGs per batch
// element (blockIdx = j*32 + b; pair (b,b+32) lands on the same XCD under
// round-robin dispatch). Per-step flag words compared by equality -> 0xAA
// poison can never false-trigger. Payload trick: only the j==0 image bakes
// gx/cx into its payload (both images read identical gx/cx), so prefetch
// registers die before the handshake and pre = own_payload + other_payload.
// ---------------------------------------------------------------------------
__global__ __launch_bounds__(512, 2) void gru_pair(
    const float* __restrict__ gx,      // [B][T][512] fp32, bias baked
    const float* __restrict__ cx,      // [B][T][256] fp32, bias baked
    const float* __restrict__ wgp,     // packed fp32 recurrent weights
    float* __restrict__ pay1, float* __restrict__ pay2,
    u32* __restrict__ flags,
    unsigned short* __restrict__ hseq) // [B][T][256] fp16 (output path only)
{
  __shared__ __align__(16) float part1[4][512];
  __shared__ __align__(16) float part2[4][256];
  __shared__ __align__(16) float h32[256];    // fp32 master h (both WGs)
  __shared__ __align__(16) float rh32[256];   // r .* h
  __shared__ __align__(16) float ug[256];     // update gate u

  const int tid = threadIdx.x;
  const int w = tid >> 6, l = tid & 63;
  const int a = w & 3, bgrp = w >> 2;
  const int b = blockIdx.x & 31;
  const int j = blockIdx.x >> 5;
  const int K0 = 128 * j;

  // ---- weight preamble: 192 fp32/thread into VGPRs (coalesced) ----
  const float* wbase = wgp + (size_t)j * 98304;
  float wg[128];
#pragma unroll
  for (int r = 0; r < 128; ++r) wg[r] = wbase[(size_t)r*512 + tid];
  float wc[64];
#pragma unroll
  for (int r = 0; r < 64; ++r) wc[r] = wbase[(size_t)(128+r)*512 + tid];

  if (tid < 256) h32[tid] = 0.f;
  __syncthreads();

  const float* gxb = gx + (size_t)b * T_ * G_;
  const float* cxb = cx + (size_t)b * T_ * H_;
  unsigned short* hb = hseq + (size_t)b * T_ * H_;

  float* p1own = pay1 + (size_t)(b*2 + j)     * 2 * 512;
  float* p1oth = pay1 + (size_t)(b*2 + (1-j)) * 2 * 512;
  float* p2own = pay2 + (size_t)(b*2 + j)     * 2 * 256;
  float* p2oth = pay2 + (size_t)(b*2 + (1-j)) * 2 * 256;
  u32* f1own = flags + ((size_t)((b*2 + j)*2 + 0) << 11);
  u32* f2own = flags + ((size_t)((b*2 + j)*2 + 1) << 11);
  u32* f1oth = flags + ((size_t)((b*2 + (1-j))*2 + 0) << 11);
  u32* f2oth = flags + ((size_t)((b*2 + (1-j))*2 + 1) << 11);

  for (int t = 0; t < T_; ++t){
    const int par = t & 1;
    // prefetch gx/cx (j==0 image only; consumed at the reduce, pre-handshake)
    f4 g4 = {0.f,0.f,0.f,0.f}, c4 = {0.f,0.f,0.f,0.f};
    if (j == 0){
      if (tid < 128) g4 = *(const f4*)(gxb + (size_t)t*G_ + 4*tid);
      if (tid < 64)  c4 = *(const f4*)(cxb + (size_t)t*H_ + 4*tid);
    }

    // ---- GEMV1 partial over own k-range ----
    float acc[4] = {0.f, 0.f, 0.f, 0.f};
#pragma unroll
    for (int c = 0; c < 2; ++c){
      float hh[16];
#pragma unroll
      for (int i = 0; i < 16; i += 4)
        *(f4*)&hh[i] = *(const f4*)&h32[K0 + 32*a + 16*c + i];
#pragma unroll
      for (int oi = 0; oi < 4; ++oi)
#pragma unroll
        for (int kk = 0; kk < 16; ++kk)
          acc[oi] = fmaf(wg[oi*32 + c*16 + kk], hh[kk], acc[oi]);
    }
#pragma unroll
    for (int oi = 0; oi < 4; ++oi)
      part1[a][256*bgrp + 64*oi + l] = acc[oi];
    __syncthreads();                                   // (A)

    f4 s1 = {0.f,0.f,0.f,0.f};
    if (tid < 128){
      s1 = *(const f4*)&part1[0][4*tid];
#pragma unroll
      for (int aa = 1; aa < 4; ++aa) s1 += *(const f4*)&part1[aa][4*tid];
      if (j == 0) s1 += g4;
      *(f4*)(p1own + par*512 + 4*tid) = s1;
    }
    __syncthreads();  // (B) all payload stores drained before flag
    if (tid == 0){
      __hip_atomic_store(f1own + t, (u32)(t+1), __ATOMIC_RELEASE, __HIP_MEMORY_SCOPE_AGENT);
      while (__hip_atomic_load(f1oth + t, __ATOMIC_ACQUIRE, __HIP_MEMORY_SCOPE_AGENT) != (u32)(t+1)) {}
    }
    __syncthreads();                                   // (C)

    // ---- gates ----
    if (tid < 128){
      f4 oth1 = *(const f4*)(p1oth + par*512 + 4*tid);
      f4 pre = s1 + oth1;
      if (tid < 64){
        f4 r;
        r.x = fsigmoid(pre.x); r.y = fsigmoid(pre.y);
        r.z = fsigmoid(pre.z); r.w = fsigmoid(pre.w);
        f4 hv = *(const f4*)&h32[4*tid];
        *(f4*)&rh32[4*tid] = r * hv;
      } else {
        f4 uv;
        uv.x = fsigmoid(pre.x); uv.y = fsigmoid(pre.y);
        uv.z = fsigmoid(pre.z); uv.w = fsigmoid(pre.w);
        *(f4*)&ug[4*tid - 256] = uv;
      }
    }
    __syncthreads();                                   // (D)

    // ---- GEMV2 partial over own k-range ----
    float ac2[2] = {0.f, 0.f};
#pragma unroll
    for (int c = 0; c < 2; ++c){
      float rr[16];
#pragma unroll
      for (int i = 0; i < 16; i += 4)
        *(f4*)&rr[i] = *(const f4*)&rh32[K0 + 32*a + 16*c + i];
#pragma unroll
      for (int oi2 = 0; oi2 < 2; ++oi2)
#pragma unroll
        for (int kk = 0; kk < 16; ++kk)
          ac2[oi2] = fmaf(wc[oi2*32 + c*16 + kk], rr[kk], ac2[oi2]);
    }
#pragma unroll
    for (int oi2 = 0; oi2 < 2; ++oi2)
      part2[a][128*bgrp + 64*oi2 + l] = ac2[oi2];
    __syncthreads();                                   // (E)

    f4 s2 = {0.f,0.f,0.f,0.f};
    if (tid < 64){
      s2 = *(const f4*)&part2[0][4*tid];
#pragma unroll
      for (int aa = 1; aa < 4; ++aa) s2 += *(const f4*)&part2[aa][4*tid];
      if (j == 0) s2 += c4;
      *(f4*)(p2own + par*256 + 4*tid) = s2;
    }
    __syncthreads();                                   // (F)
    if (tid == 0){
      __hip_atomic_store(f2own + t, (u32)(t+1), __ATOMIC_RELEASE, __HIP_MEMORY_SCOPE_AGENT);
      while (__hip_atomic_load(f2oth + t, __ATOMIC_ACQUIRE, __HIP_MEMORY_SCOPE_AGENT) != (u32)(t+1)) {}
    }
    __syncthreads();                                   // (G)

    // ---- candidate, h update (redundant full h in both WGs) ----
    if (tid < 64){
      f4 oth2 = *(const f4*)(p2oth + par*256 + 4*tid);
      f4 pre2 = s2 + oth2;
      f4 cv;
      cv.x = ftanh(pre2.x); cv.y = ftanh(pre2.y);
      cv.z = ftanh(pre2.z); cv.w = ftanh(pre2.w);
      f4 uv = *(const f4*)&ug[4*tid];
      f4 hv = *(const f4*)&h32[4*tid];
      f4 one = {1.f,1.f,1.f,1.f};
      f4 hn = uv*hv + (one - uv)*cv;
      *(f4*)&h32[4*tid] = hn;
      if (j == 0){
        uint2 pk;
        pk.x = pack2(hn.x, hn.y);
        pk.y = pack2(hn.z, hn.w);
        *(uint2*)(hb + (size_t)t*H_ + 4*tid) = pk;
      }
    }
    __syncthreads();                                   // (H)
  }
}

// ---------------------------------------------------------------------------
// Phase 3: out = sigmoid(Hseq @ Wp + bp); fp16 A (output path only), fp32 out.
// ---------------------------------------------------------------------------
__global__ __launch_bounds__(256) void out_proj(
    const unsigned short* __restrict__ hs, const float* __restrict__ Wp,
    const float* __restrict__ bp, float* __restrict__ out)
{
  __shared__ __align__(16) float At[16][64];
  __shared__ __align__(16) float Bt[16][64];
  const int t  = threadIdx.x;
  const int m0 = blockIdx.x*64, n0 = blockIdx.y*64;
  const int tm = (t & 15)*4, tn = (t >> 4)*4;
  const int lm = t >> 2,  lk = (t & 3)*4;
  const int bk = t >> 4,  bn = (t & 15)*4;
  float acc[4][4] = {};
  for (int kc = 0; kc < H_; kc += 16){
    __syncthreads();
    uint2 a2 = *(const uint2*)(hs + (size_t)(m0+lm)*H_ + kc + lk);
    f4  b4 = *(const f4*)&Wp[(size_t)(kc+bk)*256 + n0 + bn];
    h2v a0 = __builtin_bit_cast(h2v, a2.x), a1 = __builtin_bit_cast(h2v, a2.y);
    At[lk+0][lm] = (float)a0.x; At[lk+1][lm] = (float)a0.y;
    At[lk+2][lm] = (float)a1.x; At[lk+3][lm] = (float)a1.y;
    *(f4*)&Bt[bk][bn] = b4;
    __syncthreads();
#pragma unroll
    for (int k = 0; k < 16; ++k){
      f4 av = *(const f4*)&At[k][tm];
      f4 bv = *(const f4*)&Bt[k][tn];
#pragma unroll
      for (int i = 0; i < 4; ++i){
        acc[i][0] = fmaf(av[i], bv[0], acc[i][0]);
        acc[i][1] = fmaf(av[i], bv[1], acc[i][1]);
        acc[i][2] = fmaf(av[i], bv[2], acc[i][2]);
        acc[i][3] = fmaf(av[i], bv[3], acc[i][3]);
      }
    }
  }
  float b0=bp[n0+tn], b1=bp[n0+tn+1], b2=bp[n0+tn+2], b3=bp[n0+tn+3];
#pragma unroll
  for (int i = 0; i < 4; ++i){
    f4 r;
    r.x = fsigmoid(acc[i][0]+b0); r.y = fsigmoid(acc[i][1]+b1);
    r.z = fsigmoid(acc[i][2]+b2); r.w = fsigmoid(acc[i][3]+b3);
    *(f4*)&out[(size_t)(m0+tm+i)*256 + n0 + tn] = r;
  }
}

// ---------------------------------------------------------------------------
extern "C" void kernel_launch(void* const* d_in, const int* in_sizes, int n_in,
                              void* d_out, int out_size, void* d_ws, size_t ws_size,
                              hipStream_t stream)
{
  const float* x  = (const float*)d_in[0];
  const float* Wg = (const float*)d_in[1];
  const float* bg = (const float*)d_in[2];
  const float* Wc = (const float*)d_in[3];
  const float* bc = (const float*)d_in[4];
  const float* Wp = (const float*)d_in[5];
  const float* bp = (const float*)d_in[6];
  float* out = (float*)d_out;

  char* ws = (char*)d_ws;
  // layout (bytes):
  //   Gx    @ 0         : 32*2048*512*4 = 134217728
  //   Cx    @ 134217728 : 32*2048*256*4 =  67108864
  //   Hs    @ 201326592 : 32*2048*256*2 =  33554432  (fp16)
  //   wgp   @ 234881024 : 196608*4      =    786432
  //   pay1  @ 235667456 : 64*2*512*4    =    262144
  //   pay2  @ 235929600 : 64*2*256*4    =    131072
  //   flags @ 236060672 : 64*2*2048*4   =   1048576
  float* Gx = (float*)(ws);
  float* Cx = (float*)(ws + (size_t)134217728);
  unsigned short* Hs = (unsigned short*)(ws + (size_t)201326592);
  float* wgp = (float*)(ws + (size_t)234881024);
  float* pay1 = (float*)(ws + (size_t)235667456);
  float* pay2 = (float*)(ws + (size_t)235929600);
  u32* flags = (u32*)(ws + (size_t)236060672);

  pack_w<<<768, 256, 0, stream>>>(Wg, Wc, wgp);
  input_proj<<<dim3(1024, 12), 256, 0, stream>>>(x, Wg, bg, Wc, bc, Gx, Cx);
  gru_pair<<<64, 512, 0, stream>>>(Gx, Cx, wgp, pay1, pay2, flags, Hs);
  out_proj<<<dim3(1024, 4), 256, 0, stream>>>(Hs, Wp, bp, out);
}

// Round 4
// 7858.714 us; speedup vs baseline: 1.5219x; 1.4714x over previous
//
#include <hip/hip_runtime.h>

typedef unsigned int u32;
typedef unsigned long long u64;
typedef float    f4  __attribute__((ext_vector_type(4)));
typedef _Float16 h2v __attribute__((ext_vector_type(2)));

#define B_ 32
#define T_ 2048
#define D_ 256
#define H_ 256
#define G_ 512  // 2H

// Precision: GRU recurrence amplifies per-step error ~6e4x over T=2048
// (fp16 loop: absmax 0.316; fp32 loop: 0.0039). Recurrent path stays fp32.
// Capacity: 768KB fp32 recurrent weights > one CU's 512KB RF -> WG pair per
// batch element (K-split 128+128).
// Round-3 lessons:
//  (a) VGPR_Count=124: launch_bounds min-waves is only a LOWER bound; the
//      allocator targeted 4 waves/SIMD (128 regs) and spilled the weights.
//      Fix: amdgpu_waves_per_eu(2,2) pins budget at 256 + asm pin on each
//      weight defeats remat-sinking.
//  (b) WRITE_SIZE=434MB: agent release/acquire emitted buffer_wbl2+inv every
//      handshake (L2 flush storm, ~5-6k cy/step). Fix: tagged-payload
//      handshake — each payload float travels as one relaxed agent-scope
//      8B atomic (value<<32 | tag), executed at the coherent point. No
//      fences, no flag hop, placement-independent, single-buffered (tag
//      uniqueness + mutual dependency make reuse race-free; 0xAA poison
//      never matches a tag <= 2048).

__device__ __forceinline__ float fsigmoid(float x){
  return 1.f / (1.f + __expf(-x));
}
__device__ __forceinline__ float ftanh(float x){
  float a = fabsf(x);
  float e = __expf(2.f * a);
  float t = 1.f - 2.f / (e + 1.f);
  return copysignf(t, x);
}
__device__ __forceinline__ u32 pack2(float a, float b){
  h2v p = {(_Float16)a, (_Float16)b};
  return __builtin_bit_cast(u32, p);
}
__device__ __forceinline__ u64 tag_pack(float v, u32 tag){
  return ((u64)__builtin_bit_cast(u32, v) << 32) | (u64)tag;
}
__device__ __forceinline__ float tag_val(u64 x){
  return __builtin_bit_cast(float, (u32)(x >> 32));
}

// ---------------------------------------------------------------------------
// Phase 0: pack recurrent weights (fp32 bit-exact) into gru_pair's register
// layout. WG image j owns k in [128j, 128j+128). Thread t in [0,512):
// wave w=t>>6, a=w&3 (k-slice of 32), bgrp=w>>2 (out-half), lane l=t&63.
//   r in [0,128):  oi=r>>5, c=(r>>4)&1, kk=r&15
//                  -> Wg[256+128j+32a+16c+kk][256*bgrp + 64*oi + l]
//   r in [128,192): rc=r-128: oi2=rc>>5, c=(rc>>4)&1, kk=rc&15
//                  -> Wc[256+128j+32a+16c+kk][128*bgrp + 64*oi2 + l]
// Linear: wgp[j*98304 + r*512 + t]  (coalesced in gru_pair's preamble).
// ---------------------------------------------------------------------------
__global__ __launch_bounds__(256) void pack_w(
    const float* __restrict__ Wg, const float* __restrict__ Wc,
    float* __restrict__ wgp)
{
  int idx = blockIdx.x * 256 + threadIdx.x;          // [0, 196608)
  int j  = idx / 98304;
  int r2 = idx - j * 98304;
  int r = r2 >> 9;
  int t = r2 & 511;
  int w = t >> 6, l = t & 63;
  int a = w & 3, bgrp = w >> 2;
  float v;
  if (r < 128){
    int oi = r >> 5, c = (r >> 4) & 1, kk = r & 15;
    v = Wg[(size_t)(256 + 128*j + 32*a + 16*c + kk) * G_ + 256*bgrp + 64*oi + l];
  } else {
    int rc = r - 128;
    int oi2 = rc >> 5, c = (rc >> 4) & 1, kk = rc & 15;
    v = Wc[(size_t)(256 + 128*j + 32*a + 16*c + kk) * H_ + 128*bgrp + 64*oi2 + l];
  }
  wgp[idx] = v;
}

// ---------------------------------------------------------------------------
// Phase 1: Gx = X @ Wg[:256,:] + bg   [65536 x 512] fp32
//          Cx = X @ Wc[:256,:] + bc   [65536 x 256] fp32
// ---------------------------------------------------------------------------
__global__ __launch_bounds__(256) void input_proj(
    const float* __restrict__ X, const float* __restrict__ Wg, const float* __restrict__ bg,
    const float* __restrict__ Wc, const float* __restrict__ bc,
    float* __restrict__ gx, float* __restrict__ cx)
{
  __shared__ __align__(16) float At[16][64];   // [k][m]
  __shared__ __align__(16) float Bt[16][64];   // [k][n]
  const int t  = threadIdx.x;
  const int m0 = blockIdx.x*64, n0 = blockIdx.y*64;
  const int tm = (t & 15)*4, tn = (t >> 4)*4;
  const int lm = t >> 2,  lk = (t & 3)*4;
  const int bk = t >> 4,  bn = (t & 15)*4;
  const float* bsrc; int bld;
  if (n0 < G_) { bsrc = Wg + n0; bld = G_; } else { bsrc = Wc + (n0 - G_); bld = H_; }
  float acc[4][4] = {};
  for (int kc = 0; kc < D_; kc += 16){
    __syncthreads();
    f4 a4 = *(const f4*)&X[(size_t)(m0+lm)*D_ + kc + lk];
    f4 b4 = *(const f4*)&bsrc[(size_t)(kc+bk)*bld + bn];
    At[lk+0][lm] = a4.x; At[lk+1][lm] = a4.y; At[lk+2][lm] = a4.z; At[lk+3][lm] = a4.w;
    *(f4*)&Bt[bk][bn] = b4;
    __syncthreads();
#pragma unroll
    for (int k = 0; k < 16; ++k){
      f4 av = *(const f4*)&At[k][tm];
      f4 bv = *(const f4*)&Bt[k][tn];
#pragma unroll
      for (int i = 0; i < 4; ++i){
        acc[i][0] = fmaf(av[i], bv[0], acc[i][0]);
        acc[i][1] = fmaf(av[i], bv[1], acc[i][1]);
        acc[i][2] = fmaf(av[i], bv[2], acc[i][2]);
        acc[i][3] = fmaf(av[i], bv[3], acc[i][3]);
      }
    }
  }
  if (n0 < G_){
    f4 bb = { bg[n0+tn], bg[n0+tn+1], bg[n0+tn+2], bg[n0+tn+3] };
#pragma unroll
    for (int i = 0; i < 4; ++i){
      f4 v = { acc[i][0]+bb.x, acc[i][1]+bb.y, acc[i][2]+bb.z, acc[i][3]+bb.w };
      *(f4*)&gx[(size_t)(m0+tm+i)*G_ + n0 + tn] = v;
    }
  } else {
    int nn = n0 - G_;
    f4 bb = { bc[nn+tn], bc[nn+tn+1], bc[nn+tn+2], bc[nn+tn+3] };
#pragma unroll
    for (int i = 0; i < 4; ++i){
      f4 v = { acc[i][0]+bb.x, acc[i][1]+bb.y, acc[i][2]+bb.z, acc[i][3]+bb.w };
      *(f4*)&cx[(size_t)(m0+tm+i)*H_ + nn + tn] = v;
    }
  }
}

// ---------------------------------------------------------------------------
// Phase 2: sequential GRU, fp32-exact, 512 thr/WG, WG pair per batch element
// (blockIdx = j*32 + b). Weights pinned in VGPRs (waves_per_eu(2,2) => 256-reg
// budget; asm pin defeats remat). Cross-WG exchange via tagged 8B relaxed
// agent atomics at the coherent point; 4 barriers/step.
// ---------------------------------------------------------------------------
__global__ __launch_bounds__(512)
__attribute__((amdgpu_waves_per_eu(2, 2)))
void gru_pair(
    const float* __restrict__ gx,      // [B][T][512] fp32, bias baked
    const float* __restrict__ cx,      // [B][T][256] fp32, bias baked
    const float* __restrict__ wgp,     // packed fp32 recurrent weights
    u64* __restrict__ pay1, u64* __restrict__ pay2,
    unsigned short* __restrict__ hseq) // [B][T][256] fp16 (output path only)
{
  __shared__ __align__(16) float part1[4][512];
  __shared__ __align__(16) float part2[4][256];
  __shared__ __align__(16) float h32[256];    // fp32 master h (both WGs)
  __shared__ __align__(16) float rh32[256];   // r .* h
  __shared__ __align__(16) float ug[256];     // update gate u

  const int tid = threadIdx.x;
  const int w = tid >> 6, l = tid & 63;
  const int a = w & 3, bgrp = w >> 2;
  const int b = blockIdx.x & 31;
  const int j = blockIdx.x >> 5;
  const int K0 = 128 * j;

  // ---- weight preamble: 192 fp32/thread into VGPRs (coalesced) ----
  const float* wbase = wgp + (size_t)j * 98304;
  float wg[128];
#pragma unroll
  for (int r = 0; r < 128; ++r) wg[r] = wbase[(size_t)r*512 + tid];
  float wc[64];
#pragma unroll
  for (int r = 0; r < 64; ++r) wc[r] = wbase[(size_t)(128+r)*512 + tid];
  // opaque pin: values become asm-defined -> cannot be remat-sunk into the loop
#pragma unroll
  for (int r = 0; r < 128; ++r) asm volatile("" : "+v"(wg[r]));
#pragma unroll
  for (int r = 0; r < 64; ++r) asm volatile("" : "+v"(wc[r]));

  if (tid < 256) h32[tid] = 0.f;
  __syncthreads();

  const float* gxb = gx + (size_t)b * T_ * G_;
  const float* cxb = cx + (size_t)b * T_ * H_;
  unsigned short* hb = hseq + (size_t)b * T_ * H_;

  u64* p1own = pay1 + (size_t)(b*2 + j)     * 512;
  u64* p1oth = pay1 + (size_t)(b*2 + (1-j)) * 512;
  u64* p2own = pay2 + (size_t)(b*2 + j)     * 256;
  u64* p2oth = pay2 + (size_t)(b*2 + (1-j)) * 256;

  for (int t = 0; t < T_; ++t){
    const u32 tag = (u32)(t + 1);
    // prefetch gx/cx (j==0 image only; both images' payloads sum to full pre)
    f4 g4 = {0.f,0.f,0.f,0.f}, c4 = {0.f,0.f,0.f,0.f};
    if (j == 0){
      if (tid < 128) g4 = *(const f4*)(gxb + (size_t)t*G_ + 4*tid);
      if (tid < 64)  c4 = *(const f4*)(cxb + (size_t)t*H_ + 4*tid);
    }

    // ---- GEMV1 partial over own k-range ----
    float acc[4] = {0.f, 0.f, 0.f, 0.f};
#pragma unroll
    for (int c = 0; c < 2; ++c){
      float hh[16];
#pragma unroll
      for (int i = 0; i < 16; i += 4)
        *(f4*)&hh[i] = *(const f4*)&h32[K0 + 32*a + 16*c + i];
#pragma unroll
      for (int oi = 0; oi < 4; ++oi)
#pragma unroll
        for (int kk = 0; kk < 16; ++kk)
          acc[oi] = fmaf(wg[oi*32 + c*16 + kk], hh[kk], acc[oi]);
    }
#pragma unroll
    for (int oi = 0; oi < 4; ++oi)
      part1[a][256*bgrp + 64*oi + l] = acc[oi];
    __syncthreads();                                   // (A)

    if (tid < 128){
      f4 s1 = *(const f4*)&part1[0][4*tid];
#pragma unroll
      for (int aa = 1; aa < 4; ++aa) s1 += *(const f4*)&part1[aa][4*tid];
      if (j == 0) s1 += g4;
      // publish own partials (tagged, fire-and-forget)
      __hip_atomic_store(p1own + 4*tid + 0, tag_pack(s1.x, tag), __ATOMIC_RELAXED, __HIP_MEMORY_SCOPE_AGENT);
      __hip_atomic_store(p1own + 4*tid + 1, tag_pack(s1.y, tag), __ATOMIC_RELAXED, __HIP_MEMORY_SCOPE_AGENT);
      __hip_atomic_store(p1own + 4*tid + 2, tag_pack(s1.z, tag), __ATOMIC_RELAXED, __HIP_MEMORY_SCOPE_AGENT);
      __hip_atomic_store(p1own + 4*tid + 3, tag_pack(s1.w, tag), __ATOMIC_RELAXED, __HIP_MEMORY_SCOPE_AGENT);
      // poll partner's partials (self-tagged: no flag, no fences)
      u64 v0, v1, v2, v3;
      for (;;){
        v0 = __hip_atomic_load(p1oth + 4*tid + 0, __ATOMIC_RELAXED, __HIP_MEMORY_SCOPE_AGENT);
        v1 = __hip_atomic_load(p1oth + 4*tid + 1, __ATOMIC_RELAXED, __HIP_MEMORY_SCOPE_AGENT);
        v2 = __hip_atomic_load(p1oth + 4*tid + 2, __ATOMIC_RELAXED, __HIP_MEMORY_SCOPE_AGENT);
        v3 = __hip_atomic_load(p1oth + 4*tid + 3, __ATOMIC_RELAXED, __HIP_MEMORY_SCOPE_AGENT);
        if (((u32)v0 == tag) & ((u32)v1 == tag) & ((u32)v2 == tag) & ((u32)v3 == tag)) break;
      }
      f4 pre = s1;
      pre.x += tag_val(v0); pre.y += tag_val(v1);
      pre.z += tag_val(v2); pre.w += tag_val(v3);
      if (tid < 64){
        f4 r;
        r.x = fsigmoid(pre.x); r.y = fsigmoid(pre.y);
        r.z = fsigmoid(pre.z); r.w = fsigmoid(pre.w);
        f4 hv = *(const f4*)&h32[4*tid];
        *(f4*)&rh32[4*tid] = r * hv;
      } else {
        f4 uv;
        uv.x = fsigmoid(pre.x); uv.y = fsigmoid(pre.y);
        uv.z = fsigmoid(pre.z); uv.w = fsigmoid(pre.w);
        *(f4*)&ug[4*tid - 256] = uv;
      }
    }
    __syncthreads();                                   // (D)

    // ---- GEMV2 partial over own k-range ----
    float ac2[2] = {0.f, 0.f};
#pragma unroll
    for (int c = 0; c < 2; ++c){
      float rr[16];
#pragma unroll
      for (int i = 0; i < 16; i += 4)
        *(f4*)&rr[i] = *(const f4*)&rh32[K0 + 32*a + 16*c + i];
#pragma unroll
      for (int oi2 = 0; oi2 < 2; ++oi2)
#pragma unroll
        for (int kk = 0; kk < 16; ++kk)
          ac2[oi2] = fmaf(wc[oi2*32 + c*16 + kk], rr[kk], ac2[oi2]);
    }
#pragma unroll
    for (int oi2 = 0; oi2 < 2; ++oi2)
      part2[a][128*bgrp + 64*oi2 + l] = ac2[oi2];
    __syncthreads();                                   // (E)

    if (tid < 64){
      f4 s2 = *(const f4*)&part2[0][4*tid];
#pragma unroll
      for (int aa = 1; aa < 4; ++aa) s2 += *(const f4*)&part2[aa][4*tid];
      if (j == 0) s2 += c4;
      __hip_atomic_store(p2own + 4*tid + 0, tag_pack(s2.x, tag), __ATOMIC_RELAXED, __HIP_MEMORY_SCOPE_AGENT);
      __hip_atomic_store(p2own + 4*tid + 1, tag_pack(s2.y, tag), __ATOMIC_RELAXED, __HIP_MEMORY_SCOPE_AGENT);
      __hip_atomic_store(p2own + 4*tid + 2, tag_pack(s2.z, tag), __ATOMIC_RELAXED, __HIP_MEMORY_SCOPE_AGENT);
      __hip_atomic_store(p2own + 4*tid + 3, tag_pack(s2.w, tag), __ATOMIC_RELAXED, __HIP_MEMORY_SCOPE_AGENT);
      u64 v0, v1, v2, v3;
      for (;;){
        v0 = __hip_atomic_load(p2oth + 4*tid + 0, __ATOMIC_RELAXED, __HIP_MEMORY_SCOPE_AGENT);
        v1 = __hip_atomic_load(p2oth + 4*tid + 1, __ATOMIC_RELAXED, __HIP_MEMORY_SCOPE_AGENT);
        v2 = __hip_atomic_load(p2oth + 4*tid + 2, __ATOMIC_RELAXED, __HIP_MEMORY_SCOPE_AGENT);
        v3 = __hip_atomic_load(p2oth + 4*tid + 3, __ATOMIC_RELAXED, __HIP_MEMORY_SCOPE_AGENT);
        if (((u32)v0 == tag) & ((u32)v1 == tag) & ((u32)v2 == tag) & ((u32)v3 == tag)) break;
      }
      f4 pre2 = s2;
      pre2.x += tag_val(v0); pre2.y += tag_val(v1);
      pre2.z += tag_val(v2); pre2.w += tag_val(v3);
      f4 cv;
      cv.x = ftanh(pre2.x); cv.y = ftanh(pre2.y);
      cv.z = ftanh(pre2.z); cv.w = ftanh(pre2.w);
      f4 uv = *(const f4*)&ug[4*tid];
      f4 hv = *(const f4*)&h32[4*tid];
      f4 one = {1.f,1.f,1.f,1.f};
      f4 hn = uv*hv + (one - uv)*cv;
      *(f4*)&h32[4*tid] = hn;
      if (j == 0){
        uint2 pk;
        pk.x = pack2(hn.x, hn.y);
        pk.y = pack2(hn.z, hn.w);
        *(uint2*)(hb + (size_t)t*H_ + 4*tid) = pk;
      }
    }
    __syncthreads();                                   // (H)
  }
}

// ---------------------------------------------------------------------------
// Phase 3: out = sigmoid(Hseq @ Wp + bp); fp16 A (output path only), fp32 out.
// ---------------------------------------------------------------------------
__global__ __launch_bounds__(256) void out_proj(
    const unsigned short* __restrict__ hs, const float* __restrict__ Wp,
    const float* __restrict__ bp, float* __restrict__ out)
{
  __shared__ __align__(16) float At[16][64];
  __shared__ __align__(16) float Bt[16][64];
  const int t  = threadIdx.x;
  const int m0 = blockIdx.x*64, n0 = blockIdx.y*64;
  const int tm = (t & 15)*4, tn = (t >> 4)*4;
  const int lm = t >> 2,  lk = (t & 3)*4;
  const int bk = t >> 4,  bn = (t & 15)*4;
  float acc[4][4] = {};
  for (int kc = 0; kc < H_; kc += 16){
    __syncthreads();
    uint2 a2 = *(const uint2*)(hs + (size_t)(m0+lm)*H_ + kc + lk);
    f4  b4 = *(const f4*)&Wp[(size_t)(kc+bk)*256 + n0 + bn];
    h2v a0 = __builtin_bit_cast(h2v, a2.x), a1 = __builtin_bit_cast(h2v, a2.y);
    At[lk+0][lm] = (float)a0.x; At[lk+1][lm] = (float)a0.y;
    At[lk+2][lm] = (float)a1.x; At[lk+3][lm] = (float)a1.y;
    *(f4*)&Bt[bk][bn] = b4;
    __syncthreads();
#pragma unroll
    for (int k = 0; k < 16; ++k){
      f4 av = *(const f4*)&At[k][tm];
      f4 bv = *(const f4*)&Bt[k][tn];
#pragma unroll
      for (int i = 0; i < 4; ++i){
        acc[i][0] = fmaf(av[i], bv[0], acc[i][0]);
        acc[i][1] = fmaf(av[i], bv[1], acc[i][1]);
        acc[i][2] = fmaf(av[i], bv[2], acc[i][2]);
        acc[i][3] = fmaf(av[i], bv[3], acc[i][3]);
      }
    }
  }
  float b0=bp[n0+tn], b1=bp[n0+tn+1], b2=bp[n0+tn+2], b3=bp[n0+tn+3];
#pragma unroll
  for (int i = 0; i < 4; ++i){
    f4 r;
    r.x = fsigmoid(acc[i][0]+b0); r.y = fsigmoid(acc[i][1]+b1);
    r.z = fsigmoid(acc[i][2]+b2); r.w = fsigmoid(acc[i][3]+b3);
    *(f4*)&out[(size_t)(m0+tm+i)*256 + n0 + tn] = r;
  }
}

// ---------------------------------------------------------------------------
extern "C" void kernel_launch(void* const* d_in, const int* in_sizes, int n_in,
                              void* d_out, int out_size, void* d_ws, size_t ws_size,
                              hipStream_t stream)
{
  const float* x  = (const float*)d_in[0];
  const float* Wg = (const float*)d_in[1];
  const float* bg = (const float*)d_in[2];
  const float* Wc = (const float*)d_in[3];
  const float* bc = (const float*)d_in[4];
  const float* Wp = (const float*)d_in[5];
  const float* bp = (const float*)d_in[6];
  float* out = (float*)d_out;

  char* ws = (char*)d_ws;
  // layout (bytes):
  //   Gx    @ 0         : 32*2048*512*4 = 134217728
  //   Cx    @ 134217728 : 32*2048*256*4 =  67108864
  //   Hs    @ 201326592 : 32*2048*256*2 =  33554432  (fp16)
  //   wgp   @ 234881024 : 196608*4      =    786432
  //   pay1  @ 235667456 : 64*512*8      =    262144  (tagged u64)
  //   pay2  @ 235929600 : 64*256*8      =    131072  (tagged u64)
  float* Gx = (float*)(ws);
  float* Cx = (float*)(ws + (size_t)134217728);
  unsigned short* Hs = (unsigned short*)(ws + (size_t)201326592);
  float* wgp = (float*)(ws + (size_t)234881024);
  u64* pay1 = (u64*)(ws + (size_t)235667456);
  u64* pay2 = (u64*)(ws + (size_t)235929600);

  pack_w<<<768, 256, 0, stream>>>(Wg, Wc, wgp);
  input_proj<<<dim3(1024, 12), 256, 0, stream>>>(x, Wg, bg, Wc, bc, Gx, Cx);
  gru_pair<<<64, 512, 0, stream>>>(Gx, Cx, wgp, pay1, pay2, Hs);
  out_proj<<<dim3(1024, 4), 256, 0, stream>>>(Hs, Wp, bp, out);
}